// Round 4
// baseline (210.708 us; speedup 1.0000x reference)
//
#include <hip/hip_runtime.h>
#include <math.h>

// PPO loss with GAE.  B=4096 rows, T=2048 steps, fp32.
// Inputs: 0 rewards(B,T) 1 values(B,T+1) 2 ref_probs(UNUSED) 3 old_probs(B,T)
//         4 curr_probs(B,T) 5 masks(B,T)
// Output: 4 floats: total, ppo, 0.5*value_loss, 0.01*entropy_loss
//
// R4: cooperative launch rejected by harness (R3 silent no-op) -> back to the
// verified 4-dispatch structure with latency fixes:
//  - values row staged into LDS via coalesced dword loads (was stride-8 gather)
//  - block scan: wave-shuffle affine suffix scan (no barriers) + 1-barrier
//    cross-wave combine (was 8-barrier LDS Hillis-Steele)
//  - __launch_bounds__(256,8) on gae for 8 blocks/CU
//  - ppo: 12 independent float4 loads in flight per thread, rcp for divide

#define GAMMA     0.99f
#define LAM       0.95f
#define CLIP_LO   0.8f
#define CLIP_HI   1.2f
#define EPSF      1e-9f

constexpr int BB = 4096;
constexpr int TT = 2048;
constexpr long long NN = (long long)BB * TT;   // 8388608
constexpr int PPO_BLOCKS = 2048;

// ws layout:
//  [0,32)        stats: float mean, float inv_std_eps, double sum_adv2
//  [64,64+32K)   gae partials: 4096 x float2
//  [.. +16K)     ppo partials: 2048 x float2
//  [49216, +32M) raw advantages (16B aligned)
struct Stats { float mean; float inv; double sum2; };
static constexpr size_t GAE_PART_OFF = 64;
static constexpr size_t PPO_PART_OFF = 64 + 4096 * sizeof(float2);
static constexpr size_t ADV_OFF      = PPO_PART_OFF + 2048 * sizeof(float2); // 49216

// ---------------------------------------------------------------- K1: GAE scan
__global__ __launch_bounds__(256, 8) void gae_kernel(
    const float* __restrict__ rewards,
    const float* __restrict__ values,
    const float* __restrict__ masks,
    float* __restrict__ adv_out,
    float2* __restrict__ partials)
{
    const int row  = blockIdx.x;
    const int tid  = threadIdx.x;
    const int lane = tid & 63;
    const int wave = tid >> 6;
    const int t0   = tid * 8;

    __shared__ float  lv[2052];     // staged values row (2049 used)
    __shared__ float2 wT[4];        // per-wave affine totals (A,B)
    __shared__ float  wr1[4], wr2[4];

    const float* rrow = rewards + (size_t)row * TT;
    const float* mrow = masks   + (size_t)row * TT;
    const float* vrow = values  + (size_t)row * (TT + 1);

    // issue strided float4 loads for r,m first (in flight during staging)
    float4 r0 = *(const float4*)(rrow + t0);
    float4 r1 = *(const float4*)(rrow + t0 + 4);
    float4 m0 = *(const float4*)(mrow + t0);
    float4 m1 = *(const float4*)(mrow + t0 + 4);

    // coalesced staging of the values row: lane i reads consecutive dwords
#pragma unroll
    for (int k = 0; k < 8; ++k) lv[tid + 256 * k] = vrow[tid + 256 * k];
    if (tid == 0) lv[2048] = vrow[2048];
    __syncthreads();

    float r[8] = {r0.x, r0.y, r0.z, r0.w, r1.x, r1.y, r1.z, r1.w};
    float m[8] = {m0.x, m0.y, m0.z, m0.w, m1.x, m1.y, m1.z, m1.w};
    float v[9];
#pragma unroll
    for (int j = 0; j < 9; ++j) v[j] = lv[t0 + j];

    // delta[t] = r + gamma*v_next*m - v ;  c[t] = gamma*lam*m[t]
    float delta[8], c[8];
#pragma unroll
    for (int j = 0; j < 8; ++j) {
        delta[j] = r[j] + GAMMA * v[j + 1] * m[j] - v[j];
        c[j]     = (GAMMA * LAM) * m[j];
    }

    // chunk-local reverse scan (zero carry) + suffix products
    float la[8], S[8];
    la[7] = delta[7];
    S[7]  = c[7];
#pragma unroll
    for (int j = 6; j >= 0; --j) {
        la[j] = delta[j] + c[j] * la[j + 1];
        S[j]  = c[j] * S[j + 1];
    }

    // ---- wave-level suffix scan of affine fns f_i(x) = la[0] + S[0]*x ----
    // I_l = f_l o f_{l+1} o ... o f_63  (within wave), via shuffles, no barriers
    float A = S[0], Bv = la[0];
#pragma unroll
    for (int d = 1; d < 64; d <<= 1) {
        float A2 = __shfl_down(A,  d, 64);
        float B2 = __shfl_down(Bv, d, 64);
        if (lane + d < 64) {
            Bv = Bv + A * B2;   // f_l o f_{l+d..}
            A  = A * A2;
        }
    }
    // cross-wave combine: wave totals -> incoming carry C_w
    if (lane == 0) wT[wave] = make_float2(A, Bv);
    __syncthreads();
    float C = 0.0f;
    for (int ww = 3; ww > wave; --ww)      // C_w = T_{w+1} o ... o T_3 (0)
        C = wT[ww].y + wT[ww].x * C;

    float A1 = __shfl_down(A,  1, 64);
    float B1 = __shfl_down(Bv, 1, 64);
    float carry = (lane < 63) ? (B1 + A1 * C) : C;   // adv at t0+8

    float a[8], s1 = 0.f, s2 = 0.f;
#pragma unroll
    for (int j = 0; j < 8; ++j) {
        a[j] = la[j] + S[j] * carry;
        s1 += a[j];
        s2 += a[j] * a[j];
    }
    float4 o0 = {a[0], a[1], a[2], a[3]};
    float4 o1 = {a[4], a[5], a[6], a[7]};
    *(float4*)(adv_out + (size_t)row * TT + t0)     = o0;
    *(float4*)(adv_out + (size_t)row * TT + t0 + 4) = o1;

    // block reduce s1,s2 -> one float2 store per block
#pragma unroll
    for (int off = 32; off > 0; off >>= 1) {
        s1 += __shfl_down(s1, off, 64);
        s2 += __shfl_down(s2, off, 64);
    }
    if (lane == 0) { wr1[wave] = s1; wr2[wave] = s2; }
    __syncthreads();
    if (tid == 0) {
        float2 p = {wr1[0] + wr1[1] + wr1[2] + wr1[3],
                    wr2[0] + wr2[1] + wr2[2] + wr2[3]};
        partials[row] = p;
    }
}

// ------------------------------------- K2: reduce gae partials -> mean, inv_std
__global__ __launch_bounds__(256) void finalize_stats(
    const float2* __restrict__ gp, Stats* __restrict__ stats)
{
    const int tid = threadIdx.x;
    __shared__ double l1[256], l2[256];
    double s1 = 0.0, s2 = 0.0;
    for (int i = tid; i < BB; i += 256) {
        float2 p = gp[i];
        s1 += (double)p.x;
        s2 += (double)p.y;
    }
    l1[tid] = s1; l2[tid] = s2;
    __syncthreads();
    for (int st = 128; st > 0; st >>= 1) {
        if (tid < st) { l1[tid] += l1[tid + st]; l2[tid] += l2[tid + st]; }
        __syncthreads();
    }
    if (tid == 0) {
        double S1 = l1[0], S2 = l2[0];
        double mean = S1 / (double)NN;
        double var  = (S2 - S1 * S1 / (double)NN) / (double)(NN - 1); // ddof=1
        stats->mean = (float)mean;
        stats->inv  = (float)(1.0 / (sqrt(var) + 1e-9));
        stats->sum2 = S2;
    }
}

// ------------------------------------------------- K3: ppo surrogate + entropy
__global__ __launch_bounds__(256, 4) void ppo_kernel(
    const float* __restrict__ adv,
    const float* __restrict__ oldp,
    const float* __restrict__ currp,
    const Stats* __restrict__ stats,
    float2* __restrict__ partials)
{
    const float mean = stats->mean;
    const float inv  = stats->inv;
    const int tid = threadIdx.x;

    const long long base   = (long long)blockIdx.x * 256 + tid;   // float4 units
    const long long stride = (long long)PPO_BLOCKS * 256;         // 524288
    // n4 = NN/4 = 2097152 = 4 * stride exactly

    const float4* a4 = (const float4*)adv;
    const float4* o4 = (const float4*)oldp;
    const float4* c4 = (const float4*)currp;

    float4 Af[4], Of[4], Cf[4];
#pragma unroll
    for (int k = 0; k < 4; ++k) {
        long long i = base + (long long)k * stride;
        Af[k] = a4[i]; Of[k] = o4[i]; Cf[k] = c4[i];
    }

    float sm = 0.f, se = 0.f;
#pragma unroll
    for (int k = 0; k < 4; ++k) {
        float av[4] = {Af[k].x, Af[k].y, Af[k].z, Af[k].w};
        float ov[4] = {Of[k].x, Of[k].y, Of[k].z, Of[k].w};
        float cv[4] = {Cf[k].x, Cf[k].y, Cf[k].z, Cf[k].w};
#pragma unroll
        for (int j = 0; j < 4; ++j) {
            float an    = (av[j] - mean) * inv;
            float ratio = cv[j] * __builtin_amdgcn_rcpf(ov[j] + EPSF);
            float rc    = fminf(fmaxf(ratio, CLIP_LO), CLIP_HI);
            sm += fminf(ratio * an, rc * an);
            se += cv[j] * __logf(cv[j] + EPSF);
        }
    }

#pragma unroll
    for (int off = 32; off > 0; off >>= 1) {
        sm += __shfl_down(sm, off, 64);
        se += __shfl_down(se, off, 64);
    }
    __shared__ float w1[4], w2[4];
    const int wave = tid >> 6, lane = tid & 63;
    if (lane == 0) { w1[wave] = sm; w2[wave] = se; }
    __syncthreads();
    if (tid == 0) {
        float2 p = {w1[0] + w1[1] + w1[2] + w1[3],
                    w2[0] + w2[1] + w2[2] + w2[3]};
        partials[blockIdx.x] = p;
    }
}

// --------------------------------- K4: reduce ppo partials -> 4 output scalars
__global__ __launch_bounds__(256) void finalize_out(
    const float2* __restrict__ pp,
    const Stats* __restrict__ stats,
    float* __restrict__ out)
{
    const int tid = threadIdx.x;
    __shared__ double l1[256], l2[256];
    double s1 = 0.0, s2 = 0.0;
    for (int i = tid; i < PPO_BLOCKS; i += 256) {
        float2 p = pp[i];
        s1 += (double)p.x;
        s2 += (double)p.y;
    }
    l1[tid] = s1; l2[tid] = s2;
    __syncthreads();
    for (int st = 128; st > 0; st >>= 1) {
        if (tid < st) { l1[tid] += l1[tid + st]; l2[tid] += l2[tid + st]; }
        __syncthreads();
    }
    if (tid == 0) {
        double invN = 1.0 / (double)NN;
        double vl   = 0.5  * (stats->sum2 * invN);   // 0.5 * mean(raw_adv^2)
        double ppo  = -(l1[0] * invN);
        double ent  = -0.01 * (l2[0] * invN);
        out[0] = (float)(ppo + vl + ent);
        out[1] = (float)ppo;
        out[2] = (float)vl;
        out[3] = (float)ent;
    }
}

extern "C" void kernel_launch(void* const* d_in, const int* in_sizes, int n_in,
                              void* d_out, int out_size, void* d_ws, size_t ws_size,
                              hipStream_t stream) {
    const float* rewards = (const float*)d_in[0];
    const float* values  = (const float*)d_in[1];
    // d_in[2] = ref_probs: unused by the reference
    const float* oldp    = (const float*)d_in[3];
    const float* currp   = (const float*)d_in[4];
    const float* masks   = (const float*)d_in[5];

    Stats*  stats = (Stats*)d_ws;
    float2* gaep  = (float2*)((char*)d_ws + GAE_PART_OFF);
    float2* ppop  = (float2*)((char*)d_ws + PPO_PART_OFF);
    float*  advws = (float*)((char*)d_ws + ADV_OFF);
    float*  out   = (float*)d_out;

    gae_kernel<<<BB, 256, 0, stream>>>(rewards, values, masks, advws, gaep);
    finalize_stats<<<1, 256, 0, stream>>>(gaep, stats);
    ppo_kernel<<<PPO_BLOCKS, 256, 0, stream>>>(advws, oldp, currp, stats, ppop);
    finalize_out<<<1, 256, 0, stream>>>(ppop, stats, out);
}

// Round 5
// 203.501 us; speedup vs baseline: 1.0354x; 1.0354x over previous
//
#include <hip/hip_runtime.h>
#include <math.h>

// PPO loss with GAE.  B=4096 rows, T=2048 steps, fp32 inputs.
// Inputs: 0 rewards(B,T) 1 values(B,T+1) 2 ref_probs(UNUSED) 3 old_probs(B,T)
//         4 curr_probs(B,T) 5 masks(B,T)
// Output: 4 floats: total, ppo, 0.5*value_loss, 0.01*entropy_loss
//
// R5: R2/R4 identical timing -> gae is memory-footprint bound, not
// latency/scheduling bound. So: (1) adv stored as bf16 (RNE) -> halves the
// adv write+read traffic; exact fp32 sums still drive mean/std/value_loss.
// (2) gae: 2 rows per block, all loads issued up front (2x MLP), no LDS
// staging (R4's 8-way bank conflicts), verified shuffle affine scan.
// (3) ppo: 16 elems/thread, 12 coalesced loads in flight.

#define GAMMA     0.99f
#define LAM       0.95f
#define CLIP_LO   0.8f
#define CLIP_HI   1.2f
#define EPSF      1e-9f

constexpr int BB = 4096;
constexpr int TT = 2048;
constexpr long long NN = (long long)BB * TT;   // 8388608
constexpr int GAE_BLOCKS = BB / 2;             // 2048, 2 rows/block
constexpr int PPO_BLOCKS = 2048;

// ws layout:
//  [0,32)          stats: float mean, float inv_std_eps, double sum_adv2
//  [64, 64+16K)    gae partials: 2048 x float2
//  [.., +16K)      ppo partials: 2048 x float2
//  [32832, +16.8M) adv in bf16 (uint4-aligned)
struct Stats { float mean; float inv; double sum2; };
static constexpr size_t GAE_PART_OFF = 64;
static constexpr size_t PPO_PART_OFF = GAE_PART_OFF + GAE_BLOCKS * sizeof(float2);
static constexpr size_t ADV_OFF      = PPO_PART_OFF + PPO_BLOCKS * sizeof(float2); // 32832 (64-aligned)

__device__ __forceinline__ unsigned bf16_rne(float x) {
    unsigned u = __float_as_uint(x);
    u += 0x7FFFu + ((u >> 16) & 1u);
    return u >> 16;
}

// ---------------------------------------------------------------- K1: GAE scan
__global__ __launch_bounds__(256, 4) void gae_kernel(
    const float* __restrict__ rewards,
    const float* __restrict__ values,
    const float* __restrict__ masks,
    uint4* __restrict__ advb,          // bf16 x8 per uint4
    float2* __restrict__ partials)
{
    const int tid  = threadIdx.x;
    const int lane = tid & 63;
    const int wave = tid >> 6;
    const int t0   = tid * 8;
    const int row0 = blockIdx.x * 2;
    const int row1 = row0 + 1;

    __shared__ float2 wTa[4], wTb[4];
    __shared__ float  wr1[4], wr2[4];

    // ---- issue ALL loads for both rows up front (independent, 26 per thread)
    const float* ra = rewards + (size_t)row0 * TT;
    const float* ma = masks   + (size_t)row0 * TT;
    const float* va_ = values + (size_t)row0 * (TT + 1);
    const float* rb = rewards + (size_t)row1 * TT;
    const float* mb = masks   + (size_t)row1 * TT;
    const float* vb_ = values + (size_t)row1 * (TT + 1);

    float4 ra0 = *(const float4*)(ra + t0);
    float4 ra1 = *(const float4*)(ra + t0 + 4);
    float4 ma0 = *(const float4*)(ma + t0);
    float4 ma1 = *(const float4*)(ma + t0 + 4);
    float4 rb0 = *(const float4*)(rb + t0);
    float4 rb1 = *(const float4*)(rb + t0 + 4);
    float4 mb0 = *(const float4*)(mb + t0);
    float4 mb1 = *(const float4*)(mb + t0 + 4);
    float va[9], vb[9];
#pragma unroll
    for (int j = 0; j < 9; ++j) va[j] = va_[t0 + j];
#pragma unroll
    for (int j = 0; j < 9; ++j) vb[j] = vb_[t0 + j];

    float rA[8] = {ra0.x, ra0.y, ra0.z, ra0.w, ra1.x, ra1.y, ra1.z, ra1.w};
    float mA[8] = {ma0.x, ma0.y, ma0.z, ma0.w, ma1.x, ma1.y, ma1.z, ma1.w};
    float rB[8] = {rb0.x, rb0.y, rb0.z, rb0.w, rb1.x, rb1.y, rb1.z, rb1.w};
    float mB[8] = {mb0.x, mb0.y, mb0.z, mb0.w, mb1.x, mb1.y, mb1.z, mb1.w};

    // ---- per-row chunk-local reverse affine scans
    float laA[8], SA[8], laB[8], SB[8];
    {
        float d[8], c[8];
#pragma unroll
        for (int j = 0; j < 8; ++j) {
            d[j] = rA[j] + GAMMA * va[j + 1] * mA[j] - va[j];
            c[j] = (GAMMA * LAM) * mA[j];
        }
        laA[7] = d[7]; SA[7] = c[7];
#pragma unroll
        for (int j = 6; j >= 0; --j) { laA[j] = d[j] + c[j] * laA[j + 1]; SA[j] = c[j] * SA[j + 1]; }
    }
    {
        float d[8], c[8];
#pragma unroll
        for (int j = 0; j < 8; ++j) {
            d[j] = rB[j] + GAMMA * vb[j + 1] * mB[j] - vb[j];
            c[j] = (GAMMA * LAM) * mB[j];
        }
        laB[7] = d[7]; SB[7] = c[7];
#pragma unroll
        for (int j = 6; j >= 0; --j) { laB[j] = d[j] + c[j] * laB[j + 1]; SB[j] = c[j] * SB[j + 1]; }
    }

    // ---- wave-level suffix scans of affine fns (verified in R4)
    float Aa = SA[0], Ba = laA[0];
    float Ab = SB[0], Bb = laB[0];
#pragma unroll
    for (int d = 1; d < 64; d <<= 1) {
        float A2a = __shfl_down(Aa, d, 64), B2a = __shfl_down(Ba, d, 64);
        float A2b = __shfl_down(Ab, d, 64), B2b = __shfl_down(Bb, d, 64);
        if (lane + d < 64) {
            Ba = Ba + Aa * B2a;  Aa = Aa * A2a;
            Bb = Bb + Ab * B2b;  Ab = Ab * A2b;
        }
    }
    if (lane == 0) { wTa[wave] = make_float2(Aa, Ba); wTb[wave] = make_float2(Ab, Bb); }
    __syncthreads();
    float Ca = 0.0f, Cb = 0.0f;
    for (int ww = 3; ww > wave; --ww) {
        Ca = wTa[ww].y + wTa[ww].x * Ca;
        Cb = wTb[ww].y + wTb[ww].x * Cb;
    }
    float A1a = __shfl_down(Aa, 1, 64), B1a = __shfl_down(Ba, 1, 64);
    float A1b = __shfl_down(Ab, 1, 64), B1b = __shfl_down(Bb, 1, 64);
    float carA = (lane < 63) ? (B1a + A1a * Ca) : Ca;
    float carB = (lane < 63) ? (B1b + A1b * Cb) : Cb;

    // ---- final adv, fp32 sums, bf16 pack + store
    float s1 = 0.f, s2 = 0.f;
    unsigned ha[8], hb[8];
#pragma unroll
    for (int j = 0; j < 8; ++j) {
        float a = laA[j] + SA[j] * carA;
        s1 += a; s2 += a * a;
        ha[j] = bf16_rne(a);
        float b = laB[j] + SB[j] * carB;
        s1 += b; s2 += b * b;
        hb[j] = bf16_rne(b);
    }
    uint4 pa = {ha[0] | (ha[1] << 16), ha[2] | (ha[3] << 16),
                ha[4] | (ha[5] << 16), ha[6] | (ha[7] << 16)};
    uint4 pb = {hb[0] | (hb[1] << 16), hb[2] | (hb[3] << 16),
                hb[4] | (hb[5] << 16), hb[6] | (hb[7] << 16)};
    advb[row0 * 256 + tid] = pa;      // 8 bf16 = 16B per thread, coalesced
    advb[row1 * 256 + tid] = pb;

    // ---- block reduce -> one float2 per block
#pragma unroll
    for (int off = 32; off > 0; off >>= 1) {
        s1 += __shfl_down(s1, off, 64);
        s2 += __shfl_down(s2, off, 64);
    }
    if (lane == 0) { wr1[wave] = s1; wr2[wave] = s2; }
    __syncthreads();
    if (tid == 0) {
        float2 p = {wr1[0] + wr1[1] + wr1[2] + wr1[3],
                    wr2[0] + wr2[1] + wr2[2] + wr2[3]};
        partials[blockIdx.x] = p;
    }
}

// ------------------------------------- K2: reduce gae partials -> mean, inv_std
__global__ __launch_bounds__(256) void finalize_stats(
    const float2* __restrict__ gp, Stats* __restrict__ stats)
{
    const int tid = threadIdx.x;
    __shared__ double l1[256], l2[256];
    double s1 = 0.0, s2 = 0.0;
    for (int i = tid; i < GAE_BLOCKS; i += 256) {
        float2 p = gp[i];
        s1 += (double)p.x;
        s2 += (double)p.y;
    }
    l1[tid] = s1; l2[tid] = s2;
    __syncthreads();
    for (int st = 128; st > 0; st >>= 1) {
        if (tid < st) { l1[tid] += l1[tid + st]; l2[tid] += l2[tid + st]; }
        __syncthreads();
    }
    if (tid == 0) {
        double S1 = l1[0], S2 = l2[0];
        double mean = S1 / (double)NN;
        double var  = (S2 - S1 * S1 / (double)NN) / (double)(NN - 1); // ddof=1
        stats->mean = (float)mean;
        stats->inv  = (float)(1.0 / (sqrt(var) + 1e-9));
        stats->sum2 = S2;
    }
}

// ------------------------------------------------- K3: ppo surrogate + entropy
__global__ __launch_bounds__(256, 8) void ppo_kernel(
    const float* __restrict__ adv_bf16,   // raw bf16 pairs, read as uint2
    const float* __restrict__ oldp,
    const float* __restrict__ currp,
    const Stats* __restrict__ stats,
    float2* __restrict__ partials)
{
    const float mean = stats->mean;
    const float inv  = stats->inv;
    const int tid = threadIdx.x;
    const int b   = blockIdx.x;

    const uint2*  a2 = (const uint2*)adv_bf16;   // 4 bf16 per uint2
    const float4* o4 = (const float4*)oldp;
    const float4* c4 = (const float4*)currp;

    // thread handles 16 elems: 4 k-slabs of 4; lane-consecutive in each slab
    uint2  Aq[4]; float4 Of[4], Cf[4];
#pragma unroll
    for (int k = 0; k < 4; ++k) {
        int i = b * 1024 + k * 256 + tid;
        Aq[k] = a2[i]; Of[k] = o4[i]; Cf[k] = c4[i];
    }

    float sm = 0.f, se = 0.f;
#pragma unroll
    for (int k = 0; k < 4; ++k) {
        float av[4] = {__uint_as_float(Aq[k].x << 16),
                       __uint_as_float(Aq[k].x & 0xFFFF0000u),
                       __uint_as_float(Aq[k].y << 16),
                       __uint_as_float(Aq[k].y & 0xFFFF0000u)};
        float ov[4] = {Of[k].x, Of[k].y, Of[k].z, Of[k].w};
        float cv[4] = {Cf[k].x, Cf[k].y, Cf[k].z, Cf[k].w};
#pragma unroll
        for (int j = 0; j < 4; ++j) {
            float an    = (av[j] - mean) * inv;
            float ratio = cv[j] * __builtin_amdgcn_rcpf(ov[j] + EPSF);
            float rc    = fminf(fmaxf(ratio, CLIP_LO), CLIP_HI);
            sm += fminf(ratio * an, rc * an);
            se += cv[j] * __logf(cv[j] + EPSF);
        }
    }

#pragma unroll
    for (int off = 32; off > 0; off >>= 1) {
        sm += __shfl_down(sm, off, 64);
        se += __shfl_down(se, off, 64);
    }
    __shared__ float w1[4], w2[4];
    const int wave = tid >> 6, lane = tid & 63;
    if (lane == 0) { w1[wave] = sm; w2[wave] = se; }
    __syncthreads();
    if (tid == 0) {
        float2 p = {w1[0] + w1[1] + w1[2] + w1[3],
                    w2[0] + w2[1] + w2[2] + w2[3]};
        partials[b] = p;
    }
}

// --------------------------------- K4: reduce ppo partials -> 4 output scalars
__global__ __launch_bounds__(256) void finalize_out(
    const float2* __restrict__ pp,
    const Stats* __restrict__ stats,
    float* __restrict__ out)
{
    const int tid = threadIdx.x;
    __shared__ double l1[256], l2[256];
    double s1 = 0.0, s2 = 0.0;
    for (int i = tid; i < PPO_BLOCKS; i += 256) {
        float2 p = pp[i];
        s1 += (double)p.x;
        s2 += (double)p.y;
    }
    l1[tid] = s1; l2[tid] = s2;
    __syncthreads();
    for (int st = 128; st > 0; st >>= 1) {
        if (tid < st) { l1[tid] += l1[tid + st]; l2[tid] += l2[tid + st]; }
        __syncthreads();
    }
    if (tid == 0) {
        double invN = 1.0 / (double)NN;
        double vl   = 0.5  * (stats->sum2 * invN);   // 0.5 * mean(raw_adv^2)
        double ppo  = -(l1[0] * invN);
        double ent  = -0.01 * (l2[0] * invN);
        out[0] = (float)(ppo + vl + ent);
        out[1] = (float)ppo;
        out[2] = (float)vl;
        out[3] = (float)ent;
    }
}

extern "C" void kernel_launch(void* const* d_in, const int* in_sizes, int n_in,
                              void* d_out, int out_size, void* d_ws, size_t ws_size,
                              hipStream_t stream) {
    const float* rewards = (const float*)d_in[0];
    const float* values  = (const float*)d_in[1];
    // d_in[2] = ref_probs: unused by the reference
    const float* oldp    = (const float*)d_in[3];
    const float* currp   = (const float*)d_in[4];
    const float* masks   = (const float*)d_in[5];

    Stats*  stats = (Stats*)d_ws;
    float2* gaep  = (float2*)((char*)d_ws + GAE_PART_OFF);
    float2* ppop  = (float2*)((char*)d_ws + PPO_PART_OFF);
    uint4*  advb  = (uint4*)((char*)d_ws + ADV_OFF);
    float*  out   = (float*)d_out;

    gae_kernel<<<GAE_BLOCKS, 256, 0, stream>>>(rewards, values, masks, advb, gaep);
    finalize_stats<<<1, 256, 0, stream>>>(gaep, stats);
    ppo_kernel<<<PPO_BLOCKS, 256, 0, stream>>>((const float*)advb, oldp, currp, stats, ppop);
    finalize_out<<<1, 256, 0, stream>>>(ppop, stats, out);
}